// Round 5
// baseline (328.793 us; speedup 1.0000x reference)
//
#include <hip/hip_runtime.h>
#include <math.h>

#define NSUBJ 8192
#define NTT   512
#define OBS   9
#define LOG2PI 1.8378770664093453f

#define CHUNKS   16
#define REALSTEP 32          // real (ll-accumulating) steps per chunk
#define WARMSTEP 32          // warm-up steps for chunks > 0
#define SERIAL_P 48          // serial Riccati steps before steady-state fill
#define LDS_ENT  68          // LDS table entries per block (64 used + prefetch pad)

__global__ void zero_out_kernel(float* out) { out[0] = 0.0f; }

__device__ __forceinline__ float fast_rcp(float x) { return __builtin_amdgcn_rcpf(x); }

// Swap adjacent lanes (0<->1, 2<->3, ...) via DPP quad_perm [1,0,3,2].
__device__ __forceinline__ float swap1(float x) {
    int r = __builtin_amdgcn_update_dpp(0, __float_as_int(x), 0xB1, 0xF, 0xF, true);
    return __int_as_float(r);
}

// ---------------------------------------------------------------------------
// Kernel 1: data-independent Riccati recursion. Contractive; SERIAL_P serial
// steps then cooperative steady-state fill. Lane parity = regime.
// tab entry (t, regime): [Sinv(6), logc, pad] = 8 floats.
// ---------------------------------------------------------------------------
__global__ __launch_bounds__(64, 1) void precomp_kernel(
    const float* __restrict__ b1_r1, const float* __restrict__ lam1f,
    const float* __restrict__ q1d,   const float* __restrict__ b2_in,
    const float* __restrict__ lam2f, const float* __restrict__ q2d,
    const float* __restrict__ r_in,  float* __restrict__ tab)
{
    const int lane = threadIdx.x;
    const bool is2 = (lane & 1) != 0;

    float Rinv[9];
    float logdetR = 0.0f;
    #pragma unroll
    for (int i = 0; i < 9; ++i) {
        float r = fabsf(r_in[i]) + 1e-4f;
        Rinv[i] = fast_rcp(r);
        logdetR += __logf(r);
    }
    const float C0 = 9.0f * LOG2PI + logdetR;

    float Bm[9];
    {
        float a0 = b1_r1[0], a1 = b1_r1[1], a2 = b1_r1[2];
        Bm[0] = is2 ? b2_in[0] : a0;   Bm[1] = is2 ? b2_in[1] : 0.0f;
        Bm[2] = is2 ? b2_in[2] : 0.0f; Bm[3] = is2 ? b2_in[3] : 0.0f;
        Bm[4] = is2 ? b2_in[4] : a1;   Bm[5] = is2 ? b2_in[5] : 0.0f;
        Bm[6] = is2 ? b2_in[6] : 0.0f; Bm[7] = is2 ? b2_in[7] : 0.0f;
        Bm[8] = is2 ? b2_in[8] : a2;
    }
    float lam[9];
    lam[0] = 1.0f;
    lam[1] = is2 ? lam2f[0] : lam1f[0];
    lam[2] = is2 ? lam2f[1] : lam1f[1];
    lam[3] = is2 ? lam2f[2] : 1.0f;
    lam[4] = is2 ? lam2f[3] : lam1f[2];
    lam[5] = is2 ? lam2f[4] : lam1f[3];
    lam[6] = is2 ? lam2f[5] : 1.0f;
    lam[7] = is2 ? lam2f[6] : lam1f[4];
    lam[8] = is2 ? lam2f[7] : lam1f[5];

    float dA = lam[0]*lam[0]*Rinv[0] + lam[1]*lam[1]*Rinv[1] + lam[2]*lam[2]*Rinv[2];
    float dB = lam[3]*lam[3]*Rinv[3] + lam[4]*lam[4]*Rinv[4] + lam[5]*lam[5]*Rinv[5];
    float dC = lam[6]*lam[6]*Rinv[6] + lam[7]*lam[7]*Rinv[7] + lam[8]*lam[8]*Rinv[8];
    float Dd0 = is2 ? (dA + dB + dC) : dA;
    float Dd1 = is2 ? 0.0f : dB;
    float Dd2 = is2 ? 0.0f : dC;

    float Q0 = fabsf(is2 ? q2d[0] : q1d[0]) + 1e-4f;
    float Q1 = fabsf(is2 ? q2d[1] : q1d[1]) + 1e-4f;
    float Q2 = fabsf(is2 ? q2d[2] : q1d[2]) + 1e-4f;

    float P0 = 1000.0f, P1s = 0.0f, P2s = 0.0f, P3 = 1000.0f, P4 = 0.0f, P5 = 1000.0f;
    float Sv0, Sv1, Sv2, Sv3, Sv4, Sv5, logc;

    #pragma unroll 1
    for (int t = 0; t < SERIAL_P; ++t) {
        float M00 = Bm[0]*P0  + Bm[1]*P1s + Bm[2]*P2s;
        float M01 = Bm[0]*P1s + Bm[1]*P3  + Bm[2]*P4;
        float M02 = Bm[0]*P2s + Bm[1]*P4  + Bm[2]*P5;
        float M10 = Bm[3]*P0  + Bm[4]*P1s + Bm[5]*P2s;
        float M11 = Bm[3]*P1s + Bm[4]*P3  + Bm[5]*P4;
        float M12 = Bm[3]*P2s + Bm[4]*P4  + Bm[5]*P5;
        float M20 = Bm[6]*P0  + Bm[7]*P1s + Bm[8]*P2s;
        float M21 = Bm[6]*P1s + Bm[7]*P3  + Bm[8]*P4;
        float M22 = Bm[6]*P2s + Bm[7]*P4  + Bm[8]*P5;

        float pp00 = M00*Bm[0] + M01*Bm[1] + M02*Bm[2] + Q0;
        float pp01 = M00*Bm[3] + M01*Bm[4] + M02*Bm[5];
        float pp02 = M00*Bm[6] + M01*Bm[7] + M02*Bm[8];
        float pp11 = M10*Bm[3] + M11*Bm[4] + M12*Bm[5] + Q1;
        float pp12 = M10*Bm[6] + M11*Bm[7] + M12*Bm[8];
        float pp22 = M20*Bm[6] + M21*Bm[7] + M22*Bm[8] + Q2;

        float c00 = pp11*pp22 - pp12*pp12;
        float c01 = pp02*pp12 - pp01*pp22;
        float c02 = pp01*pp12 - pp02*pp11;
        float c11 = pp00*pp22 - pp02*pp02;
        float c12 = pp01*pp02 - pp00*pp12;
        float c22 = pp00*pp11 - pp01*pp01;
        float detP = pp00*c00 + pp01*c01 + pp02*c02;
        float idet = fast_rcp(detP);

        float s00 = c00*idet + Dd0;
        float s01 = c01*idet;
        float s02 = c02*idet;
        float s11 = c11*idet + Dd1;
        float s12 = c12*idet;
        float s22 = c22*idet + Dd2;

        float E00 = s11*s22 - s12*s12;
        float E01 = s02*s12 - s01*s22;
        float E02 = s01*s12 - s02*s11;
        float E11 = s00*s22 - s02*s02;
        float E12 = s01*s02 - s00*s12;
        float E22 = s00*s11 - s01*s01;
        float detS = s00*E00 + s01*E01 + s02*E02;
        float idetS = fast_rcp(detS);

        Sv0 = E00*idetS; Sv1 = E01*idetS; Sv2 = E02*idetS;
        Sv3 = E11*idetS; Sv4 = E12*idetS; Sv5 = E22*idetS;
        logc = -0.5f * (C0 + __logf(detP * detS));

        if (lane < 2) {
            float4* tv = (float4*)tab + (size_t)(t * 2 + lane) * 2;
            tv[0] = make_float4(Sv0, Sv1, Sv2, Sv3);
            tv[1] = make_float4(Sv4, Sv5, logc, 0.0f);
        }
        P0 = Sv0; P1s = Sv1; P2s = Sv2; P3 = Sv3; P4 = Sv4; P5 = Sv5;
    }

    // Cooperative steady-state fill: pair p fills t = SERIAL_P+p, +32, ...
    const int par = lane & 1;
    for (int t = SERIAL_P + (lane >> 1); t < NTT; t += 32) {
        float4* tv = (float4*)tab + (size_t)(t * 2 + par) * 2;
        tv[0] = make_float4(Sv0, Sv1, Sv2, Sv3);
        tv[1] = make_float4(Sv4, Sv5, logc, 0.0f);
    }
}

// ---------------------------------------------------------------------------
// Kernel 2: time-chunked per-subject recursion. Two lanes per subject
// (even = regime 1, odd = regime 2). 16 chunks of 32 real steps; chunks > 0
// prepend 32 warm-up steps. Split warm/real loops (no per-step flag).
// ---------------------------------------------------------------------------
__global__ __launch_bounds__(64, 4) void rskf_main(
    const float* __restrict__ y,
    const float* __restrict__ b1_r1, const float* __restrict__ lam1f,
    const float* __restrict__ b2_in, const float* __restrict__ lam2f,
    const float* __restrict__ r_in,
    const float* __restrict__ g1p, const float* __restrict__ g2p,
    const float* __restrict__ g3p, const float* __restrict__ g4p,
    const float* __restrict__ tab_g, float* __restrict__ out)
{
    const int chunk = blockIdx.x & (CHUNKS - 1);
    const int sgrp  = blockIdx.x / CHUNKS;
    const int subj  = sgrp * 32 + (threadIdx.x >> 1);
    const int par   = threadIdx.x & 1;
    const bool is2  = par != 0;

    const int slice0 = (chunk == 0) ? 0 : chunk * REALSTEP - WARMSTEP;
    const int nsteps = (chunk == 0) ? REALSTEP : (WARMSTEP + REALSTEP);
    const int warmN  = nsteps - REALSTEP;

    // table slice -> LDS (4.3 KB). Load up to LDS_ENT entries, clamped to table end.
    __shared__ float tab[LDS_ENT * 2 * 8];
    {
        int navail = NTT - slice0;
        int nload4 = (navail < LDS_ENT ? navail : LDS_ENT) * 4;
        const float4* src = (const float4*)tab_g + (size_t)slice0 * 4;
        float4* dst = (float4*)tab;
        #pragma unroll 1
        for (int i = threadIdx.x; i < nload4; i += 64) dst[i] = src[i];
    }
    __syncthreads();

    float Rinv[9];
    #pragma unroll
    for (int i = 0; i < 9; ++i) Rinv[i] = fast_rcp(fabsf(r_in[i]) + 1e-4f);

    float Bm[9];
    {
        float a0 = b1_r1[0], a1 = b1_r1[1], a2 = b1_r1[2];
        Bm[0] = is2 ? b2_in[0] : a0;   Bm[1] = is2 ? b2_in[1] : 0.0f;
        Bm[2] = is2 ? b2_in[2] : 0.0f; Bm[3] = is2 ? b2_in[3] : 0.0f;
        Bm[4] = is2 ? b2_in[4] : a1;   Bm[5] = is2 ? b2_in[5] : 0.0f;
        Bm[6] = is2 ? b2_in[6] : 0.0f; Bm[7] = is2 ? b2_in[7] : 0.0f;
        Bm[8] = is2 ? b2_in[8] : a2;
    }
    float lam[9];
    lam[0] = 1.0f;
    lam[1] = is2 ? lam2f[0] : lam1f[0];
    lam[2] = is2 ? lam2f[1] : lam1f[1];
    lam[3] = is2 ? lam2f[2] : 1.0f;
    lam[4] = is2 ? lam2f[3] : lam1f[2];
    lam[5] = is2 ? lam2f[4] : lam1f[3];
    lam[6] = is2 ? lam2f[5] : 1.0f;
    lam[7] = is2 ? lam2f[6] : lam1f[4];
    lam[8] = is2 ? lam2f[7] : lam1f[5];

    const float gs  = is2 ? g3p[0] : g1p[0];
    const float gv0 = is2 ? g4p[0] : g2p[0];
    const float gv1 = is2 ? g4p[1] : g2p[1];
    const float gv2 = is2 ? g4p[2] : g2p[2];

    float e0 = 0.0f, e1 = 0.0f, e2 = 0.0f;
    float mA = (chunk == 0) ? (is2 ? 0.01f : 0.99f) : 0.5f;
    float mB = 1.0f - mA;
    float llacc = 0.0f;

    const float* ybase = y + (size_t)subj * (NTT * OBS) + (size_t)slice0 * OBS;
    // last in-bounds prefetch target (never consumed when clamped)
    const float* ymax = ybase + (size_t)(nsteps - 2) * OBS;

    float ya[9], yb[9];
    #pragma unroll
    for (int j = 0; j < 9; ++j) { ya[j] = ybase[j]; yb[j] = ybase[9 + j]; }

    const float4* tvp = (const float4*)tab + par * 2;
    float4 taA0 = tvp[0], taA1 = tvp[1];
    float4 taB0 = tvp[4], taB1 = tvp[5];
    const float4* tp = tvp + 8;          // prefetch stream (entry i+2)

    auto step = [&](float (&buf)[9], const float* ldy,
                    float4& ta0, float4& ta1, const float4* tnx, bool real) {
        float S00 = ta0.x, S01 = ta0.y, S02 = ta0.z, S11 = ta0.w;
        float S12 = ta1.x, S22 = ta1.y, logc = ta1.z;
        ta0 = tnx[0];
        ta1 = tnx[1];

        float d   = gs + e0*gv0 + e1*gv1 + e2*gv2;
        float sig = fast_rcp(1.0f + __expf(-d));
        float oth = swap1(sig);
        float mp  = sig * mA + (1.0f - oth) * mB;
        float lmp = __logf(mp + 1e-9f);

        float ep0 = Bm[0]*e0 + Bm[1]*e1 + Bm[2]*e2;
        float ep1 = Bm[3]*e0 + Bm[4]*e1 + Bm[5]*e2;
        float ep2 = Bm[6]*e0 + Bm[7]*e1 + Bm[8]*e2;
        float es1 = is2 ? ep0 : ep1;
        float es2 = is2 ? ep0 : ep2;

        float v0 = buf[0] - lam[0]*ep0;
        float v1 = buf[1] - lam[1]*ep0;
        float v2 = buf[2] - lam[2]*ep0;
        float v3 = buf[3] - lam[3]*es1;
        float v4 = buf[4] - lam[4]*es1;
        float v5 = buf[5] - lam[5]*es1;
        float v6 = buf[6] - lam[6]*es2;
        float v7 = buf[7] - lam[7]*es2;
        float v8 = buf[8] - lam[8]*es2;

        // buf consumed: prefetch y two steps ahead (clamped, vectorized)
        {
            const float* lp = (ldy < ymax) ? ldy : ymax;
            float4 t0, t1;
            __builtin_memcpy(&t0, lp, 16);
            __builtin_memcpy(&t1, lp + 4, 16);
            buf[0] = t0.x; buf[1] = t0.y; buf[2] = t0.z; buf[3] = t0.w;
            buf[4] = t1.x; buf[5] = t1.y; buf[6] = t1.z; buf[7] = t1.w;
            buf[8] = lp[8];
        }

        float vr0 = v0*Rinv[0], vr1 = v1*Rinv[1], vr2 = v2*Rinv[2];
        float vr3 = v3*Rinv[3], vr4 = v4*Rinv[4], vr5 = v5*Rinv[5];
        float vr6 = v6*Rinv[6], vr7 = v7*Rinv[7], vr8 = v8*Rinv[8];
        float vRv = v0*vr0 + v1*vr1 + v2*vr2 + v3*vr3 + v4*vr4
                  + v5*vr5 + v6*vr6 + v7*vr7 + v8*vr8;

        float pA = lam[0]*vr0 + lam[1]*vr1 + lam[2]*vr2;
        float pB = lam[3]*vr3 + lam[4]*vr4 + lam[5]*vr5;
        float pC = lam[6]*vr6 + lam[7]*vr7 + lam[8]*vr8;
        float t0v = is2 ? (pA + pB + pC) : pA;
        float t1v = is2 ? 0.0f : pB;
        float t2v = is2 ? 0.0f : pC;

        float x0 = S00*t0v + S01*t1v + S02*t2v;
        float x1 = S01*t0v + S11*t1v + S12*t2v;
        float x2 = S02*t0v + S12*t1v + S22*t2v;
        float quad = t0v*x0 + t1v*x1 + t2v*x2;

        float llo = logc - 0.5f*vRv + 0.5f*quad;

        e0 = ep0 + x0; e1 = ep1 + x1; e2 = ep2 + x2;

        float lj  = llo + lmp;
        float ljo = swap1(lj);
        float u   = ljo - lj;
        float et  = __expf(-fabsf(u));
        float r   = fast_rcp(1.0f + et);
        if (real) llacc += fmaxf(lj, ljo) + __logf(1.0f + et);
        mA = (u <= 0.0f) ? r : et * r;
        mB = 1.0f - mA;
    };

    const float* pl = ybase + 18;
    int i = 0;
    #pragma unroll 1
    for (; i < warmN; i += 2) {          // warm-up: no ll accumulation
        step(ya, pl,     taA0, taA1, tp,     false);
        step(yb, pl + 9, taB0, taB1, tp + 4, false);
        pl += 18; tp += 8;
    }
    #pragma unroll 1
    for (; i < nsteps; i += 2) {         // real steps
        step(ya, pl,     taA0, taA1, tp,     true);
        step(yb, pl + 9, taB0, taB1, tp + 4, true);
        pl += 18; tp += 8;
    }

    // wave reduction; lane pair double-counts -> 0.5
    float v = llacc;
    v += __shfl_down(v, 32);
    v += __shfl_down(v, 16);
    v += __shfl_down(v, 8);
    v += __shfl_down(v, 4);
    v += __shfl_down(v, 2);
    v += __shfl_down(v, 1);
    if (threadIdx.x == 0) atomicAdd(out, -0.5f * v);
}

extern "C" void kernel_launch(void* const* d_in, const int* in_sizes, int n_in,
                              void* d_out, int out_size, void* d_ws, size_t ws_size,
                              hipStream_t stream) {
    const float* y      = (const float*)d_in[0];
    const float* b1_r1  = (const float*)d_in[1];
    const float* lam1f  = (const float*)d_in[2];
    const float* q1d    = (const float*)d_in[3];
    const float* b2     = (const float*)d_in[4];
    const float* lam2f  = (const float*)d_in[5];
    const float* q2d    = (const float*)d_in[6];
    const float* r_in   = (const float*)d_in[7];
    const float* g1     = (const float*)d_in[8];
    const float* g2     = (const float*)d_in[9];
    const float* g3     = (const float*)d_in[10];
    const float* g4     = (const float*)d_in[11];
    float* out = (float*)d_out;
    float* tab = (float*)d_ws;          // 512*2*8 floats = 32 KB

    hipLaunchKernelGGL(zero_out_kernel, dim3(1), dim3(1), 0, stream, out);
    hipLaunchKernelGGL(precomp_kernel, dim3(1), dim3(64), 0, stream,
                       b1_r1, lam1f, q1d, b2, lam2f, q2d, r_in, tab);
    hipLaunchKernelGGL(rskf_main, dim3((NSUBJ / 32) * CHUNKS), dim3(64), 0, stream,
                       y, b1_r1, lam1f, b2, lam2f, r_in, g1, g2, g3, g4, tab, out);
}

// Round 6
// 292.789 us; speedup vs baseline: 1.1230x; 1.1230x over previous
//
#include <hip/hip_runtime.h>
#include <math.h>

#define NSUBJ 8192
#define NTT   512
#define OBS   9
#define LOG2PI 1.8378770664093453f

#define CHUNKS   8
#define REALSTEP 64
#define WARMSTEP 64
#define SERIAL_P 48
#define LDS_ENT  132         // 128 steps + prefetch pad

__device__ __forceinline__ float fast_rcp(float x) { return __builtin_amdgcn_rcpf(x); }

// pair swap (0<->1) via quad_perm [1,0,3,2]
__device__ __forceinline__ float swap1(float x) {
    int r = __builtin_amdgcn_update_dpp(0, __float_as_int(x), 0xB1, 0xF, 0xF, true);
    return __int_as_float(r);
}
// broadcast even lane of pair to both: quad_perm [0,0,2,2] = 0xA0
__device__ __forceinline__ float bcast_even(float x) {
    int r = __builtin_amdgcn_update_dpp(0, __float_as_int(x), 0xA0, 0xF, 0xF, true);
    return __int_as_float(r);
}
// broadcast odd lane of pair to both: quad_perm [1,1,3,3] = 0xF5
__device__ __forceinline__ float bcast_odd(float x) {
    int r = __builtin_amdgcn_update_dpp(0, __float_as_int(x), 0xF5, 0xF, 0xF, true);
    return __int_as_float(r);
}

__device__ __forceinline__ float f4elem(const float4& v, int j) {
    return j == 0 ? v.x : j == 1 ? v.y : j == 2 ? v.z : v.w;
}

// ---------------------------------------------------------------------------
// Kernel 1: Riccati precompute (contractive; SERIAL_P serial steps + fill).
// Also zeroes the output (replaces zero_out kernel).
// ---------------------------------------------------------------------------
__global__ __launch_bounds__(64, 1) void precomp_kernel(
    const float* __restrict__ b1_r1, const float* __restrict__ lam1f,
    const float* __restrict__ q1d,   const float* __restrict__ b2_in,
    const float* __restrict__ lam2f, const float* __restrict__ q2d,
    const float* __restrict__ r_in,  float* __restrict__ tab,
    float* __restrict__ out)
{
    const int lane = threadIdx.x;
    if (lane == 0) out[0] = 0.0f;
    const bool is2 = (lane & 1) != 0;

    float Rinv[9];
    float logdetR = 0.0f;
    #pragma unroll
    for (int i = 0; i < 9; ++i) {
        float r = fabsf(r_in[i]) + 1e-4f;
        Rinv[i] = fast_rcp(r);
        logdetR += __logf(r);
    }
    const float C0 = 9.0f * LOG2PI + logdetR;

    float Bm[9];
    {
        float a0 = b1_r1[0], a1 = b1_r1[1], a2 = b1_r1[2];
        Bm[0] = is2 ? b2_in[0] : a0;   Bm[1] = is2 ? b2_in[1] : 0.0f;
        Bm[2] = is2 ? b2_in[2] : 0.0f; Bm[3] = is2 ? b2_in[3] : 0.0f;
        Bm[4] = is2 ? b2_in[4] : a1;   Bm[5] = is2 ? b2_in[5] : 0.0f;
        Bm[6] = is2 ? b2_in[6] : 0.0f; Bm[7] = is2 ? b2_in[7] : 0.0f;
        Bm[8] = is2 ? b2_in[8] : a2;
    }
    float lam[9];
    lam[0] = 1.0f;
    lam[1] = is2 ? lam2f[0] : lam1f[0];
    lam[2] = is2 ? lam2f[1] : lam1f[1];
    lam[3] = is2 ? lam2f[2] : 1.0f;
    lam[4] = is2 ? lam2f[3] : lam1f[2];
    lam[5] = is2 ? lam2f[4] : lam1f[3];
    lam[6] = is2 ? lam2f[5] : 1.0f;
    lam[7] = is2 ? lam2f[6] : lam1f[4];
    lam[8] = is2 ? lam2f[7] : lam1f[5];

    float dA = lam[0]*lam[0]*Rinv[0] + lam[1]*lam[1]*Rinv[1] + lam[2]*lam[2]*Rinv[2];
    float dB = lam[3]*lam[3]*Rinv[3] + lam[4]*lam[4]*Rinv[4] + lam[5]*lam[5]*Rinv[5];
    float dC = lam[6]*lam[6]*Rinv[6] + lam[7]*lam[7]*Rinv[7] + lam[8]*lam[8]*Rinv[8];
    float Dd0 = is2 ? (dA + dB + dC) : dA;
    float Dd1 = is2 ? 0.0f : dB;
    float Dd2 = is2 ? 0.0f : dC;

    float Q0 = fabsf(is2 ? q2d[0] : q1d[0]) + 1e-4f;
    float Q1 = fabsf(is2 ? q2d[1] : q1d[1]) + 1e-4f;
    float Q2 = fabsf(is2 ? q2d[2] : q1d[2]) + 1e-4f;

    float P0 = 1000.0f, P1s = 0.0f, P2s = 0.0f, P3 = 1000.0f, P4 = 0.0f, P5 = 1000.0f;
    float Sv0, Sv1, Sv2, Sv3, Sv4, Sv5, logc;

    #pragma unroll 1
    for (int t = 0; t < SERIAL_P; ++t) {
        float M00 = Bm[0]*P0  + Bm[1]*P1s + Bm[2]*P2s;
        float M01 = Bm[0]*P1s + Bm[1]*P3  + Bm[2]*P4;
        float M02 = Bm[0]*P2s + Bm[1]*P4  + Bm[2]*P5;
        float M10 = Bm[3]*P0  + Bm[4]*P1s + Bm[5]*P2s;
        float M11 = Bm[3]*P1s + Bm[4]*P3  + Bm[5]*P4;
        float M12 = Bm[3]*P2s + Bm[4]*P4  + Bm[5]*P5;
        float M20 = Bm[6]*P0  + Bm[7]*P1s + Bm[8]*P2s;
        float M21 = Bm[6]*P1s + Bm[7]*P3  + Bm[8]*P4;
        float M22 = Bm[6]*P2s + Bm[7]*P4  + Bm[8]*P5;

        float pp00 = M00*Bm[0] + M01*Bm[1] + M02*Bm[2] + Q0;
        float pp01 = M00*Bm[3] + M01*Bm[4] + M02*Bm[5];
        float pp02 = M00*Bm[6] + M01*Bm[7] + M02*Bm[8];
        float pp11 = M10*Bm[3] + M11*Bm[4] + M12*Bm[5] + Q1;
        float pp12 = M10*Bm[6] + M11*Bm[7] + M12*Bm[8];
        float pp22 = M20*Bm[6] + M21*Bm[7] + M22*Bm[8] + Q2;

        float c00 = pp11*pp22 - pp12*pp12;
        float c01 = pp02*pp12 - pp01*pp22;
        float c02 = pp01*pp12 - pp02*pp11;
        float c11 = pp00*pp22 - pp02*pp02;
        float c12 = pp01*pp02 - pp00*pp12;
        float c22 = pp00*pp11 - pp01*pp01;
        float detP = pp00*c00 + pp01*c01 + pp02*c02;
        float idet = fast_rcp(detP);

        float s00 = c00*idet + Dd0;
        float s01 = c01*idet;
        float s02 = c02*idet;
        float s11 = c11*idet + Dd1;
        float s12 = c12*idet;
        float s22 = c22*idet + Dd2;

        float E00 = s11*s22 - s12*s12;
        float E01 = s02*s12 - s01*s22;
        float E02 = s01*s12 - s02*s11;
        float E11 = s00*s22 - s02*s02;
        float E12 = s01*s02 - s00*s12;
        float E22 = s00*s11 - s01*s01;
        float detS = s00*E00 + s01*E01 + s02*E02;
        float idetS = fast_rcp(detS);

        Sv0 = E00*idetS; Sv1 = E01*idetS; Sv2 = E02*idetS;
        Sv3 = E11*idetS; Sv4 = E12*idetS; Sv5 = E22*idetS;
        logc = -0.5f * (C0 + __logf(detP * detS));

        if (lane < 2) {
            float4* tv = (float4*)tab + (size_t)(t * 2 + lane) * 2;
            tv[0] = make_float4(Sv0, Sv1, Sv2, Sv3);
            tv[1] = make_float4(Sv4, Sv5, logc, 0.0f);
        }
        P0 = Sv0; P1s = Sv1; P2s = Sv2; P3 = Sv3; P4 = Sv4; P5 = Sv5;
    }

    const int par = lane & 1;
    for (int t = SERIAL_P + (lane >> 1); t < NTT; t += 32) {
        float4* tv = (float4*)tab + (size_t)(t * 2 + par) * 2;
        tv[0] = make_float4(Sv0, Sv1, Sv2, Sv3);
        tv[1] = make_float4(Sv4, Sv5, logc, 0.0f);
    }
}

// ---------------------------------------------------------------------------
// Kernel 2: time-chunked recursion, 2 lanes/subject (even=regime1, odd=2).
// y loaded in 4-step granules: even lane fetches granule 2b+2, odd 2b+3
// (no pair duplication, 9 aligned dwordx4 per 8 steps), exchanged via DPP
// pair-broadcast at body start. 8-step unrolled body.
// ---------------------------------------------------------------------------
__global__ __launch_bounds__(64, 2) void rskf_main(
    const float* __restrict__ y,
    const float* __restrict__ b1_r1, const float* __restrict__ lam1f,
    const float* __restrict__ b2_in, const float* __restrict__ lam2f,
    const float* __restrict__ r_in,
    const float* __restrict__ g1p, const float* __restrict__ g2p,
    const float* __restrict__ g3p, const float* __restrict__ g4p,
    const float* __restrict__ tab_g, float* __restrict__ out)
{
    const int sgrp  = blockIdx.x & 255;        // 256 subject groups
    const int chunk = blockIdx.x >> 8;         // chunk-major: same sgrp -> same XCD slot
    const int subj  = sgrp * 32 + (threadIdx.x >> 1);
    const int par   = threadIdx.x & 1;
    const bool is2  = par != 0;

    const int slice0 = (chunk == 0) ? 0 : chunk * REALSTEP - WARMSTEP;
    const int nsteps = (chunk == 0) ? REALSTEP : (WARMSTEP + REALSTEP);
    const int nbody  = nsteps >> 3;
    const int warmB  = (nsteps - REALSTEP) >> 3;   // warm bodies
    const int gmax   = (nsteps >> 2) - 1;          // last valid granule

    __shared__ float tab[LDS_ENT * 2 * 8];
    {
        int navail = NTT - slice0;
        int nload4 = (navail < LDS_ENT ? navail : LDS_ENT) * 4;
        const float4* src = (const float4*)tab_g + (size_t)slice0 * 4;
        float4* dst = (float4*)tab;
        #pragma unroll 1
        for (int i = threadIdx.x; i < nload4; i += 64) dst[i] = src[i];
    }
    __syncthreads();

    float Rinv[9];
    #pragma unroll
    for (int i = 0; i < 9; ++i) Rinv[i] = fast_rcp(fabsf(r_in[i]) + 1e-4f);

    float Bm[9];
    {
        float a0 = b1_r1[0], a1 = b1_r1[1], a2 = b1_r1[2];
        Bm[0] = is2 ? b2_in[0] : a0;   Bm[1] = is2 ? b2_in[1] : 0.0f;
        Bm[2] = is2 ? b2_in[2] : 0.0f; Bm[3] = is2 ? b2_in[3] : 0.0f;
        Bm[4] = is2 ? b2_in[4] : a1;   Bm[5] = is2 ? b2_in[5] : 0.0f;
        Bm[6] = is2 ? b2_in[6] : 0.0f; Bm[7] = is2 ? b2_in[7] : 0.0f;
        Bm[8] = is2 ? b2_in[8] : a2;
    }
    float lam[9];
    lam[0] = 1.0f;
    lam[1] = is2 ? lam2f[0] : lam1f[0];
    lam[2] = is2 ? lam2f[1] : lam1f[1];
    lam[3] = is2 ? lam2f[2] : 1.0f;
    lam[4] = is2 ? lam2f[3] : lam1f[2];
    lam[5] = is2 ? lam2f[4] : lam1f[3];
    lam[6] = is2 ? lam2f[5] : 1.0f;
    lam[7] = is2 ? lam2f[6] : lam1f[4];
    lam[8] = is2 ? lam2f[7] : lam1f[5];

    const float gs  = is2 ? g3p[0] : g1p[0];
    const float gv0 = is2 ? g4p[0] : g2p[0];
    const float gv1 = is2 ? g4p[1] : g2p[1];
    const float gv2 = is2 ? g4p[2] : g2p[2];

    float e0 = 0.0f, e1 = 0.0f, e2 = 0.0f;
    float mA = (chunk == 0) ? (is2 ? 0.01f : 0.99f) : 0.5f;
    float mB = 1.0f - mA;
    float llacc = 0.0f;

    const float* ysl = y + (size_t)subj * (NTT * OBS) + (size_t)slice0 * OBS;

    // prologue: even lane loads granule 0, odd loads granule 1 (9 x dwordx4)
    float4 raw4[9];
    {
        const float4* gp = (const float4*)(ysl + (size_t)par * 36);
        #pragma unroll
        for (int i = 0; i < 9; ++i) raw4[i] = gp[i];
    }

    const float4* tvp = (const float4*)tab + par * 2;
    float4 taA0 = tvp[0], taA1 = tvp[1];
    float4 taB0 = tvp[4], taB1 = tvp[5];

    auto step = [&](const float* yv, float4& ta0, float4& ta1,
                    const float4* tnx, bool real) {
        float S00 = ta0.x, S01 = ta0.y, S02 = ta0.z, S11 = ta0.w;
        float S12 = ta1.x, S22 = ta1.y, logc = ta1.z;
        ta0 = tnx[0];
        ta1 = tnx[1];

        float d   = gs + e0*gv0 + e1*gv1 + e2*gv2;
        float sig = fast_rcp(1.0f + __expf(-d));
        float oth = swap1(sig);
        float mp  = sig * mA + (1.0f - oth) * mB;
        float lmp = __logf(mp + 1e-9f);

        float ep0 = Bm[0]*e0 + Bm[1]*e1 + Bm[2]*e2;
        float ep1 = Bm[3]*e0 + Bm[4]*e1 + Bm[5]*e2;
        float ep2 = Bm[6]*e0 + Bm[7]*e1 + Bm[8]*e2;
        float es1 = is2 ? ep0 : ep1;
        float es2 = is2 ? ep0 : ep2;

        float v0 = yv[0] - lam[0]*ep0;
        float v1 = yv[1] - lam[1]*ep0;
        float v2 = yv[2] - lam[2]*ep0;
        float v3 = yv[3] - lam[3]*es1;
        float v4 = yv[4] - lam[4]*es1;
        float v5 = yv[5] - lam[5]*es1;
        float v6 = yv[6] - lam[6]*es2;
        float v7 = yv[7] - lam[7]*es2;
        float v8 = yv[8] - lam[8]*es2;

        float vr0 = v0*Rinv[0], vr1 = v1*Rinv[1], vr2 = v2*Rinv[2];
        float vr3 = v3*Rinv[3], vr4 = v4*Rinv[4], vr5 = v5*Rinv[5];
        float vr6 = v6*Rinv[6], vr7 = v7*Rinv[7], vr8 = v8*Rinv[8];
        float vRv = v0*vr0 + v1*vr1 + v2*vr2 + v3*vr3 + v4*vr4
                  + v5*vr5 + v6*vr6 + v7*vr7 + v8*vr8;

        float pA = lam[0]*vr0 + lam[1]*vr1 + lam[2]*vr2;
        float pB = lam[3]*vr3 + lam[4]*vr4 + lam[5]*vr5;
        float pC = lam[6]*vr6 + lam[7]*vr7 + lam[8]*vr8;
        float t0v = is2 ? (pA + pB + pC) : pA;
        float t1v = is2 ? 0.0f : pB;
        float t2v = is2 ? 0.0f : pC;

        float x0 = S00*t0v + S01*t1v + S02*t2v;
        float x1 = S01*t0v + S11*t1v + S12*t2v;
        float x2 = S02*t0v + S12*t1v + S22*t2v;
        float quad = t0v*x0 + t1v*x1 + t2v*x2;

        float llo = logc - 0.5f*vRv + 0.5f*quad;

        e0 = ep0 + x0; e1 = ep1 + x1; e2 = ep2 + x2;

        float lj  = llo + lmp;
        float ljo = swap1(lj);
        float u   = ljo - lj;
        float et  = __expf(-fabsf(u));
        float r   = fast_rcp(1.0f + et);
        float lm  = fmaxf(lj, ljo) + __logf(1.0f + et);
        llacc += real ? lm : 0.0f;
        mA = (u <= 0.0f) ? r : et * r;
        mB = 1.0f - mA;
    };

    #pragma unroll 1
    for (int b = 0; b < nbody; ++b) {
        // broadcast raw granules to pair partner (even's -> bcA, odd's -> bcB)
        float bcA[36], bcB[36];
        #pragma unroll
        for (int j = 0; j < 36; ++j) {
            float rj = f4elem(raw4[j >> 2], j & 3);
            bcA[j] = bcast_even(rj);
            bcB[j] = bcast_odd(rj);
        }
        // issue next body's loads: even lane granule 2b+2, odd 2b+3 (clamped)
        {
            int ofs = 2 * b + 2 + par;
            ofs = ofs > gmax ? gmax : ofs;
            const float4* gp = (const float4*)(ysl + (size_t)ofs * 36);
            #pragma unroll
            for (int i = 0; i < 9; ++i) raw4[i] = gp[i];
        }
        const bool real = b >= warmB;
        const float4* tb = tvp + (size_t)(8 * b + 2) * 4;
        step(&bcA[0],  taA0, taA1, tb,      real);
        step(&bcA[9],  taB0, taB1, tb + 4,  real);
        step(&bcA[18], taA0, taA1, tb + 8,  real);
        step(&bcA[27], taB0, taB1, tb + 12, real);
        step(&bcB[0],  taA0, taA1, tb + 16, real);
        step(&bcB[9],  taB0, taB1, tb + 20, real);
        step(&bcB[18], taA0, taA1, tb + 24, real);
        step(&bcB[27], taB0, taB1, tb + 28, real);
    }

    float v = llacc;
    v += __shfl_down(v, 32);
    v += __shfl_down(v, 16);
    v += __shfl_down(v, 8);
    v += __shfl_down(v, 4);
    v += __shfl_down(v, 2);
    v += __shfl_down(v, 1);
    if (threadIdx.x == 0) atomicAdd(out, -0.5f * v);
}

extern "C" void kernel_launch(void* const* d_in, const int* in_sizes, int n_in,
                              void* d_out, int out_size, void* d_ws, size_t ws_size,
                              hipStream_t stream) {
    const float* y      = (const float*)d_in[0];
    const float* b1_r1  = (const float*)d_in[1];
    const float* lam1f  = (const float*)d_in[2];
    const float* q1d    = (const float*)d_in[3];
    const float* b2     = (const float*)d_in[4];
    const float* lam2f  = (const float*)d_in[5];
    const float* q2d    = (const float*)d_in[6];
    const float* r_in   = (const float*)d_in[7];
    const float* g1     = (const float*)d_in[8];
    const float* g2     = (const float*)d_in[9];
    const float* g3     = (const float*)d_in[10];
    const float* g4     = (const float*)d_in[11];
    float* out = (float*)d_out;
    float* tab = (float*)d_ws;          // 512*2*8 floats = 32 KB

    hipLaunchKernelGGL(precomp_kernel, dim3(1), dim3(64), 0, stream,
                       b1_r1, lam1f, q1d, b2, lam2f, q2d, r_in, tab, out);
    hipLaunchKernelGGL(rskf_main, dim3(256 * CHUNKS), dim3(64), 0, stream,
                       y, b1_r1, lam1f, b2, lam2f, r_in, g1, g2, g3, g4, tab, out);
}